// Round 1
// baseline (531.970 us; speedup 1.0000x reference)
//
#include <hip/hip_runtime.h>

#define NI 8
#define NF 100
#define NH 40
#define NC 40
#define NM 41
#define BSZ 2048
#define BT 64

// ---------------------------------------------------------------------------
// K1: W[i][c][f][h] = sum_m A[i][c][f][m] * Bp[i][c][m][h]
//     also writes WT[i][c][h][f] (transposed copy) so both passes of K2 can
//     read LDS rows with stride-1 float4s.
// ---------------------------------------------------------------------------
__global__ __launch_bounds__(256) void build_w_kernel(
    const float* __restrict__ A, const float* __restrict__ Bp,
    float* __restrict__ W, float* __restrict__ WT)
{
    __shared__ float As[NF * NM];   // 4100 floats
    __shared__ float Bs[NM * NH];   // 1640 floats
    const int ic = blockIdx.x;      // i*NC + c, 0..319
    const float* Ap  = A  + (size_t)ic * NF * NM;
    const float* Bpp = Bp + (size_t)ic * NM * NH;
    for (int idx = threadIdx.x; idx < NF * NM; idx += 256) As[idx] = Ap[idx];
    for (int idx = threadIdx.x; idx < NM * NH; idx += 256) Bs[idx] = Bpp[idx];
    __syncthreads();
    float* Wp  = W  + (size_t)ic * NF * NH;
    float* WTp = WT + (size_t)ic * NH * NF;
    for (int idx = threadIdx.x; idx < NF * NH; idx += 256) {
        const int f = idx / NH;
        const int h = idx % NH;
        float acc = 0.f;
        #pragma unroll
        for (int m = 0; m < NM; ++m) acc += As[f * NM + m] * Bs[m * NH + h];
        Wp[idx] = acc;
        WTp[h * NF + f] = acc;
    }
}

// ---------------------------------------------------------------------------
// K2: fused forward per (b-tile of 64, instance i).
//   pass1: hs[b][h]  = sum_c mask * (x[b,:] @ W_ic)       (W LDS: [f][h])
//   pass2: out[b][f] = relu(sum_c mask * (hs[b,:] @ W_ic^T) + b_final)
//          (WT LDS: [h][f])
// ---------------------------------------------------------------------------
__global__ __launch_bounds__(256) void fused_kernel(
    const float* __restrict__ x, const float* __restrict__ mask,
    const float* __restrict__ b_final,
    const float* __restrict__ W, const float* __restrict__ WT,
    float* __restrict__ out)
{
    __shared__ __align__(16) float xo[BT * NF];  // x tile (pass1) / out tile (pass2): 25.6 KB
    __shared__ __align__(16) float Ws[NF * NH];  // W_ic (pass1) / WT_ic (pass2): 16 KB
    __shared__ float hs[BT * NH];                // 10.24 KB
    __shared__ float ms[BT];

    const int tid = threadIdx.x;
    const int i   = blockIdx.x % NI;
    const int b0  = (blockIdx.x / NI) * BT;

    // stage x tile, zero h accumulators
    for (int idx = tid; idx < BT * NF; idx += 256) {
        const int b = idx / NF, f = idx % NF;
        xo[idx] = x[((size_t)(b0 + b) * NI + i) * NF + f];
    }
    for (int idx = tid; idx < BT * NH; idx += 256) hs[idx] = 0.f;

    const float* Wi  = W  + (size_t)i * NC * NF * NH;
    const float* WTi = WT + (size_t)i * NC * NH * NF;

    // -------- pass 1 --------
    for (int c = 0; c < NC; ++c) {
        __syncthreads();  // protect Ws/ms from previous iteration's readers
        const float* Wc = Wi + (size_t)c * NF * NH;
        for (int idx = tid; idx < NF * NH; idx += 256) Ws[idx] = Wc[idx];
        if (tid < BT) ms[tid] = mask[((size_t)(b0 + tid) * NI + i) * NC + c];
        __syncthreads();

        // items: 16 b-quads x 10 h-quads = 160
        for (int it = tid; it < (BT / 4) * (NH / 4); it += 256) {
            const int bq = it / (NH / 4);
            const int hq = it % (NH / 4);
            const int b  = bq * 4;
            const float m0 = ms[b], m1 = ms[b + 1], m2 = ms[b + 2], m3 = ms[b + 3];
            if (m0 + m1 + m2 + m3 == 0.f) continue;  // all four rows gated off
            float4 a0 = make_float4(0.f, 0.f, 0.f, 0.f);
            float4 a1 = a0, a2 = a0, a3 = a0;
            #pragma unroll 4
            for (int f = 0; f < NF; ++f) {
                const float4 w = *(const float4*)&Ws[f * NH + hq * 4];
                const float x0 = xo[(b + 0) * NF + f];
                const float x1 = xo[(b + 1) * NF + f];
                const float x2 = xo[(b + 2) * NF + f];
                const float x3 = xo[(b + 3) * NF + f];
                a0.x += x0 * w.x; a0.y += x0 * w.y; a0.z += x0 * w.z; a0.w += x0 * w.w;
                a1.x += x1 * w.x; a1.y += x1 * w.y; a1.z += x1 * w.z; a1.w += x1 * w.w;
                a2.x += x2 * w.x; a2.y += x2 * w.y; a2.z += x2 * w.z; a2.w += x2 * w.w;
                a3.x += x3 * w.x; a3.y += x3 * w.y; a3.z += x3 * w.z; a3.w += x3 * w.w;
            }
            float* h0 = &hs[(b + 0) * NH + hq * 4];
            float* h1 = &hs[(b + 1) * NH + hq * 4];
            float* h2 = &hs[(b + 2) * NH + hq * 4];
            float* h3 = &hs[(b + 3) * NH + hq * 4];
            h0[0] += m0 * a0.x; h0[1] += m0 * a0.y; h0[2] += m0 * a0.z; h0[3] += m0 * a0.w;
            h1[0] += m1 * a1.x; h1[1] += m1 * a1.y; h1[2] += m1 * a1.z; h1[3] += m1 * a1.w;
            h2[0] += m2 * a2.x; h2[1] += m2 * a2.y; h2[2] += m2 * a2.z; h2[3] += m2 * a2.w;
            h3[0] += m3 * a3.x; h3[1] += m3 * a3.y; h3[2] += m3 * a3.z; h3[3] += m3 * a3.w;
        }
    }

    __syncthreads();  // pass1 done reading xo; hs complete
    for (int idx = tid; idx < BT * NF; idx += 256) xo[idx] = 0.f;  // xo becomes out tile

    // -------- pass 2 --------
    for (int c = 0; c < NC; ++c) {
        __syncthreads();
        const float* Wc = WTi + (size_t)c * NH * NF;   // WT_ic: [h][f]
        for (int idx = tid; idx < NH * NF; idx += 256) Ws[idx] = Wc[idx];
        if (tid < BT) ms[tid] = mask[((size_t)(b0 + tid) * NI + i) * NC + c];
        __syncthreads();

        // items: 16 b-quads x 25 f-quads = 400
        for (int it = tid; it < (BT / 4) * (NF / 4); it += 256) {
            const int bq = it / (NF / 4);
            const int fq = it % (NF / 4);
            const int b  = bq * 4;
            const float m0 = ms[b], m1 = ms[b + 1], m2 = ms[b + 2], m3 = ms[b + 3];
            if (m0 + m1 + m2 + m3 == 0.f) continue;
            float4 a0 = make_float4(0.f, 0.f, 0.f, 0.f);
            float4 a1 = a0, a2 = a0, a3 = a0;
            #pragma unroll 4
            for (int h = 0; h < NH; ++h) {
                const float4 w = *(const float4*)&Ws[h * NF + fq * 4];
                const float h0 = hs[(b + 0) * NH + h];
                const float h1 = hs[(b + 1) * NH + h];
                const float h2 = hs[(b + 2) * NH + h];
                const float h3 = hs[(b + 3) * NH + h];
                a0.x += h0 * w.x; a0.y += h0 * w.y; a0.z += h0 * w.z; a0.w += h0 * w.w;
                a1.x += h1 * w.x; a1.y += h1 * w.y; a1.z += h1 * w.z; a1.w += h1 * w.w;
                a2.x += h2 * w.x; a2.y += h2 * w.y; a2.z += h2 * w.z; a2.w += h2 * w.w;
                a3.x += h3 * w.x; a3.y += h3 * w.y; a3.z += h3 * w.z; a3.w += h3 * w.w;
            }
            float* o0 = &xo[(b + 0) * NF + fq * 4];
            float* o1 = &xo[(b + 1) * NF + fq * 4];
            float* o2 = &xo[(b + 2) * NF + fq * 4];
            float* o3 = &xo[(b + 3) * NF + fq * 4];
            o0[0] += m0 * a0.x; o0[1] += m0 * a0.y; o0[2] += m0 * a0.z; o0[3] += m0 * a0.w;
            o1[0] += m1 * a1.x; o1[1] += m1 * a1.y; o1[2] += m1 * a1.z; o1[3] += m1 * a1.w;
            o2[0] += m2 * a2.x; o2[1] += m2 * a2.y; o2[2] += m2 * a2.z; o2[3] += m2 * a2.w;
            o3[0] += m3 * a3.x; o3[1] += m3 * a3.y; o3[2] += m3 * a3.z; o3[3] += m3 * a3.w;
        }
    }

    __syncthreads();
    // epilogue: bias + relu, coalesced store
    for (int idx = tid; idx < BT * NF; idx += 256) {
        const int b = idx / NF, f = idx % NF;
        const float v = xo[idx] + b_final[i * NF + f];
        out[((size_t)(b0 + b) * NI + i) * NF + f] = fmaxf(v, 0.f);
    }
}

extern "C" void kernel_launch(void* const* d_in, const int* in_sizes, int n_in,
                              void* d_out, int out_size, void* d_ws, size_t ws_size,
                              hipStream_t stream) {
    const float* x       = (const float*)d_in[0];  // (2048, 8, 100)
    const float* tk_mask = (const float*)d_in[1];  // (2048, 8, 40)
    const float* A       = (const float*)d_in[2];  // (8, 40, 100, 41)
    const float* Bp      = (const float*)d_in[3];  // (8, 40, 41, 40)
    const float* b_final = (const float*)d_in[4];  // (8, 100)
    float* out = (float*)d_out;                    // (2048, 8, 100)

    // workspace: W (8*40*100*40 f32 = 5.12 MB) then WT (same size)
    float* W  = (float*)d_ws;
    float* WT = W + (size_t)NI * NC * NF * NH;     // 1,280,000 floats each

    build_w_kernel<<<NI * NC, 256, 0, stream>>>(A, Bp, W, WT);
    fused_kernel<<<(BSZ / BT) * NI, 256, 0, stream>>>(x, tk_mask, b_final, W, WT, out);
}

// Round 2
// 124.411 us; speedup vs baseline: 4.2759x; 4.2759x over previous
//
#include <hip/hip_runtime.h>

#define NI 8
#define NF 100
#define NH 40
#define NC 40
#define NM 41
#define BSZ 2048
#define BT 64

typedef __attribute__((ext_vector_type(8))) short bf16x8;
typedef __attribute__((ext_vector_type(4))) float f32x4;
typedef __attribute__((ext_vector_type(4))) unsigned int u32x4;

__device__ __forceinline__ unsigned short f2bf(float f) {
    unsigned int u = __builtin_bit_cast(unsigned int, f);
    u += 0x7fffu + ((u >> 16) & 1u);
    return (unsigned short)(u >> 16);
}
__device__ __forceinline__ float bf2f(unsigned short s) {
    unsigned int u = ((unsigned int)s) << 16;
    return __builtin_bit_cast(float, u);
}

// ---------------------------------------------------------------------------
// K1: W_ic = A_ic @ B_ic (fp32 in LDS), then emit bf16 MFMA B-fragments:
//   Wb1: pass1 B operand, B[k=f][n=h], padded to K=128, N=48.
//        layout: [ic][nt(3)][k(4)][lane(64)] of 8 bf16 (one dwordx4 per entry)
//        lane: n = nt*16 + (lane&15), k-els f = k*32 + (lane>>4)*8 + j
//   Wb2: pass2 B operand, B[k=h][n=f], padded to K=64, N=112.
//        layout: [ic][nt(7)][kk(2)][lane(64)] of 8 bf16
//        lane: n = nt*16 + (lane&15), k-els h = kk*32 + (lane>>4)*8 + j
// ---------------------------------------------------------------------------
__global__ __launch_bounds__(256) void build_w_kernel(
    const float* __restrict__ A, const float* __restrict__ Bp,
    unsigned short* __restrict__ Wb1, unsigned short* __restrict__ Wb2)
{
    __shared__ float As[NF * NM];
    __shared__ float Bs[NM * NH];
    __shared__ float Ws[NF * NH];
    const int ic = blockIdx.x;  // i*NC + c
    const float* Ap  = A  + (size_t)ic * NF * NM;
    const float* Bpp = Bp + (size_t)ic * NM * NH;
    for (int idx = threadIdx.x; idx < NF * NM; idx += 256) As[idx] = Ap[idx];
    for (int idx = threadIdx.x; idx < NM * NH; idx += 256) Bs[idx] = Bpp[idx];
    __syncthreads();
    for (int idx = threadIdx.x; idx < NF * NH; idx += 256) {
        const int f = idx / NH;
        const int h = idx % NH;
        float acc = 0.f;
        #pragma unroll
        for (int m = 0; m < NM; ++m) acc += As[f * NM + m] * Bs[m * NH + h];
        Ws[idx] = acc;
    }
    __syncthreads();

    // Wb1 fragments: 3*4*64 = 768 entries of 16B
    for (int e = threadIdx.x; e < 768; e += 256) {
        const int nt = e >> 8, k = (e >> 6) & 3, ln = e & 63;
        const int col = ln & 15, quad = ln >> 4;
        const int h = nt * 16 + col;
        unsigned int w[4];
        #pragma unroll
        for (int jj = 0; jj < 4; ++jj) {
            const int f0 = k * 32 + quad * 8 + jj * 2;
            const int f1 = f0 + 1;
            const unsigned int lo = (f0 < NF && h < NH) ? f2bf(Ws[f0 * NH + h]) : 0;
            const unsigned int hi = (f1 < NF && h < NH) ? f2bf(Ws[f1 * NH + h]) : 0;
            w[jj] = lo | (hi << 16);
        }
        ((u32x4*)Wb1)[(size_t)ic * 768 + e] = (u32x4){w[0], w[1], w[2], w[3]};
    }
    // Wb2 fragments: 7*2*64 = 896 entries of 16B
    for (int e = threadIdx.x; e < 896; e += 256) {
        const int nt = e >> 7, kk = (e >> 6) & 1, ln = e & 63;
        const int col = ln & 15, quad = ln >> 4;
        const int f = nt * 16 + col;
        unsigned int w[4];
        #pragma unroll
        for (int jj = 0; jj < 4; ++jj) {
            const int h0 = kk * 32 + quad * 8 + jj * 2;
            const int h1 = h0 + 1;
            const unsigned int lo = (f < NF && h0 < NH) ? f2bf(Ws[f * NH + h0]) : 0;
            const unsigned int hi = (f < NF && h1 < NH) ? f2bf(Ws[f * NH + h1]) : 0;
            w[jj] = lo | (hi << 16);
        }
        ((u32x4*)Wb2)[(size_t)ic * 896 + e] = (u32x4){w[0], w[1], w[2], w[3]};
    }
}

// ---------------------------------------------------------------------------
// Fused MFMA kernel. One block = (64 b's, one i). 512 threads = 8 waves.
// pass1: wave g handles c = g, g+8, ... (5 c's). H_g = sum m.*(X @ Wc).
//        X (64x128 bf16, padded) lives in registers as A-frags for all waves.
//        partials -> LDS (bf16), 8-way reduce -> pass2 A frags (h, K=40 pad 64).
// pass2: wave g: b-half = g>>2, c = (g&3), +4, ... (10 c's).
//        out partials (4 per b-half) -> LDS bf16 -> reduce + bias + relu.
// No LDS use inside the c-loops; B-frags stream from L2 as dwordx4.
// ---------------------------------------------------------------------------
__global__ __launch_bounds__(512, 2) void fused_kernel(
    const float* __restrict__ x, const float* __restrict__ mask,
    const float* __restrict__ b_final,
    const unsigned short* __restrict__ Wb1, const unsigned short* __restrict__ Wb2,
    float* __restrict__ out)
{
    __shared__ unsigned char msx[BT * NC];               // 2560 B, 0/1 mask
    __shared__ __align__(16) unsigned short region[28672]; // 57344 B union:
    // pass1: hsP[g(8)][b(64)][h(48)]  (24576 shorts)
    // pass2: outP[hb(2)][p(4)][bl(32)][f(112)] (28672 shorts)

    const int tid  = threadIdx.x;
    const int lane = tid & 63;
    const int wav  = tid >> 6;       // 0..7
    const int col  = lane & 15;
    const int quad = lane >> 4;
    const int i    = blockIdx.x % NI;
    const int b0   = (blockIdx.x / NI) * BT;

    // ---- stage mask tile (bytes) ----
    for (int idx = tid; idx < BT * NC; idx += 512) {
        const int b = idx / NC, c = idx % NC;
        msx[idx] = mask[((size_t)(b0 + b) * NI + i) * NC + c] > 0.5f ? 1 : 0;
    }

    // ---- build X A-fragments in registers: a1[mt][k], M=64, K=128(pad) ----
    bf16x8 a1[4][4];
    #pragma unroll
    for (int mt = 0; mt < 4; ++mt) {
        const int b = b0 + mt * 16 + col;
        const float* xrow = x + ((size_t)b * NI + i) * NF;
        #pragma unroll
        for (int k = 0; k < 4; ++k) {
            #pragma unroll
            for (int j = 0; j < 8; ++j) {
                const int f = k * 32 + quad * 8 + j;
                a1[mt][k][j] = (short)((f < NF) ? f2bf(xrow[f]) : 0);
            }
        }
    }
    __syncthreads();  // msx ready

    // ---- pass 1: H[mt][nt] accumulators (M=64, N=48) ----
    f32x4 H[4][3];
    #pragma unroll
    for (int mt = 0; mt < 4; ++mt)
        #pragma unroll
        for (int nt = 0; nt < 3; ++nt)
            H[mt][nt] = (f32x4){0.f, 0.f, 0.f, 0.f};

    for (int c = wav; c < NC; c += 8) {
        const u32x4* wb1 = (const u32x4*)Wb1 + (size_t)(i * NC + c) * 768;
        u32x4 braw[3][4];
        #pragma unroll
        for (int nt = 0; nt < 3; ++nt)
            #pragma unroll
            for (int k = 0; k < 4; ++k)
                braw[nt][k] = wb1[(nt * 4 + k) * 64 + lane];
        float mrow[4][4];
        #pragma unroll
        for (int mt = 0; mt < 4; ++mt)
            #pragma unroll
            for (int r = 0; r < 4; ++r)
                mrow[mt][r] = (float)msx[(mt * 16 + quad * 4 + r) * NC + c];
        #pragma unroll
        for (int mt = 0; mt < 4; ++mt) {
            #pragma unroll
            for (int nt = 0; nt < 3; ++nt) {
                f32x4 P = (f32x4){0.f, 0.f, 0.f, 0.f};
                #pragma unroll
                for (int k = 0; k < 4; ++k) {
                    P = __builtin_amdgcn_mfma_f32_16x16x32_bf16(
                        a1[mt][k], __builtin_bit_cast(bf16x8, braw[nt][k]), P, 0, 0, 0);
                }
                #pragma unroll
                for (int r = 0; r < 4; ++r)
                    H[mt][nt][r] += mrow[mt][r] * P[r];
            }
        }
    }

    // ---- write per-wave H partials (bf16): hsP[wav][b][h] ----
    #pragma unroll
    for (int mt = 0; mt < 4; ++mt)
        #pragma unroll
        for (int nt = 0; nt < 3; ++nt)
            #pragma unroll
            for (int r = 0; r < 4; ++r) {
                const int b = mt * 16 + quad * 4 + r;
                const int h = nt * 16 + col;
                region[(wav * 64 + b) * 48 + h] = f2bf(H[mt][nt][r]);
            }
    __syncthreads();

    // ---- 8-way reduce into slot 0 ----
    for (int idx = tid; idx < BT * NH; idx += 512) {
        const int b = idx / NH, h = idx % NH;
        float s = 0.f;
        #pragma unroll
        for (int g = 0; g < 8; ++g) s += bf2f(region[(g * 64 + b) * 48 + h]);
        region[b * 48 + h] = f2bf(s);
    }
    __syncthreads();

    // ---- build pass2 A-frags: a2[mt2][kk], wave's b-half, K=40 pad 64 ----
    const int hb = wav >> 2;   // b-half
    const int cp = wav & 3;    // c-phase
    bf16x8 a2[2][2];
    #pragma unroll
    for (int mt2 = 0; mt2 < 2; ++mt2) {
        const int b = hb * 32 + mt2 * 16 + col;
        #pragma unroll
        for (int kk = 0; kk < 2; ++kk) {
            #pragma unroll
            for (int j = 0; j < 8; ++j) {
                const int h = kk * 32 + quad * 8 + j;
                a2[mt2][kk][j] = (short)((h < NH) ? region[b * 48 + h] : 0);
            }
        }
    }
    __syncthreads();  // everyone done reading hsP before outP overwrites region

    // ---- pass 2: O[mt2][nt] accumulators (M=32, N=112) ----
    f32x4 O[2][7];
    #pragma unroll
    for (int mt2 = 0; mt2 < 2; ++mt2)
        #pragma unroll
        for (int nt = 0; nt < 7; ++nt)
            O[mt2][nt] = (f32x4){0.f, 0.f, 0.f, 0.f};

    for (int c = cp; c < NC; c += 4) {
        const u32x4* wb2 = (const u32x4*)Wb2 + (size_t)(i * NC + c) * 896;
        u32x4 b2raw[7][2];
        #pragma unroll
        for (int nt = 0; nt < 7; ++nt)
            #pragma unroll
            for (int kk = 0; kk < 2; ++kk)
                b2raw[nt][kk] = wb2[(nt * 2 + kk) * 64 + lane];
        float mrow2[2][4];
        #pragma unroll
        for (int mt2 = 0; mt2 < 2; ++mt2)
            #pragma unroll
            for (int r = 0; r < 4; ++r)
                mrow2[mt2][r] = (float)msx[(hb * 32 + mt2 * 16 + quad * 4 + r) * NC + c];
        #pragma unroll
        for (int mt2 = 0; mt2 < 2; ++mt2) {
            #pragma unroll
            for (int nt = 0; nt < 7; ++nt) {
                f32x4 P = (f32x4){0.f, 0.f, 0.f, 0.f};
                #pragma unroll
                for (int kk = 0; kk < 2; ++kk) {
                    P = __builtin_amdgcn_mfma_f32_16x16x32_bf16(
                        a2[mt2][kk], __builtin_bit_cast(bf16x8, b2raw[nt][kk]), P, 0, 0, 0);
                }
                #pragma unroll
                for (int r = 0; r < 4; ++r)
                    O[mt2][nt][r] += mrow2[mt2][r] * P[r];
            }
        }
    }

    // ---- write out partials (bf16): outP[hb][cp][bl][f] ----
    #pragma unroll
    for (int mt2 = 0; mt2 < 2; ++mt2)
        #pragma unroll
        for (int nt = 0; nt < 7; ++nt)
            #pragma unroll
            for (int r = 0; r < 4; ++r) {
                const int bl = mt2 * 16 + quad * 4 + r;
                const int f  = nt * 16 + col;
                region[((hb * 4 + cp) * 32 + bl) * 112 + f] = f2bf(O[mt2][nt][r]);
            }
    __syncthreads();

    // ---- final: 4-way reduce + bias + relu, coalesced store ----
    for (int idx = tid; idx < BT * NF; idx += 512) {
        const int b = idx / NF, f = idx % NF;
        const int hb2 = b >> 5, bl = b & 31;
        float s = 0.f;
        #pragma unroll
        for (int p = 0; p < 4; ++p)
            s += bf2f(region[((hb2 * 4 + p) * 32 + bl) * 112 + f]);
        const float v = s + b_final[i * NF + f];
        out[((size_t)(b0 + b) * NI + i) * NF + f] = fmaxf(v, 0.f);
    }
}

extern "C" void kernel_launch(void* const* d_in, const int* in_sizes, int n_in,
                              void* d_out, int out_size, void* d_ws, size_t ws_size,
                              hipStream_t stream) {
    const float* x       = (const float*)d_in[0];  // (2048, 8, 100)
    const float* tk_mask = (const float*)d_in[1];  // (2048, 8, 40)
    const float* A       = (const float*)d_in[2];  // (8, 40, 100, 41)
    const float* Bp      = (const float*)d_in[3];  // (8, 40, 41, 40)
    const float* b_final = (const float*)d_in[4];  // (8, 100)
    float* out = (float*)d_out;                    // (2048, 8, 100)

    // workspace: Wb1 (320*768*8 bf16 = 3.93 MB) + Wb2 (320*896*8 bf16 = 4.59 MB)
    unsigned short* Wb1 = (unsigned short*)d_ws;
    unsigned short* Wb2 = Wb1 + (size_t)NI * NC * 768 * 8;

    build_w_kernel<<<NI * NC, 256, 0, stream>>>(A, Bp, Wb1, Wb2);
    fused_kernel<<<(BSZ / BT) * NI, 512, 0, stream>>>(x, tk_mask, b_final, Wb1, Wb2, out);
}

// Round 3
// 114.321 us; speedup vs baseline: 4.6533x; 1.0883x over previous
//
#include <hip/hip_runtime.h>

#define NI 8
#define NF 100
#define NH 40
#define NC 40
#define NM 41
#define BSZ 2048
#define BT 64
#define XPAD 104   // x-tile LDS row stride (floats), zero-padded 100..103

typedef __attribute__((ext_vector_type(8))) short bf16x8;
typedef __attribute__((ext_vector_type(4))) float f32x4;
typedef __attribute__((ext_vector_type(4))) unsigned int u32x4;

__device__ __forceinline__ unsigned short f2bf(float f) {
    unsigned int u = __builtin_bit_cast(unsigned int, f);
    u += 0x7fffu + ((u >> 16) & 1u);
    return (unsigned short)(u >> 16);
}
__device__ __forceinline__ float bf2f(unsigned short s) {
    unsigned int u = ((unsigned int)s) << 16;
    return __builtin_bit_cast(float, u);
}
__device__ __forceinline__ bf16x8 pack8(float4 u, float4 v) {
    u32x4 w;
    w.x = (unsigned int)f2bf(u.x) | ((unsigned int)f2bf(u.y) << 16);
    w.y = (unsigned int)f2bf(u.z) | ((unsigned int)f2bf(u.w) << 16);
    w.z = (unsigned int)f2bf(v.x) | ((unsigned int)f2bf(v.y) << 16);
    w.w = (unsigned int)f2bf(v.z) | ((unsigned int)f2bf(v.w) << 16);
    return __builtin_bit_cast(bf16x8, w);
}

// ---------------------------------------------------------------------------
// K1: W_ic = A_ic @ B_ic (fp32, vectorized LDS), then emit bf16 MFMA B-frags.
//   Wb1: pass1 B operand, B[k=f][n=h], padded K=128, N=48.
//        [ic][nt(3)][k(4)][lane(64)] x 16B; n=nt*16+(lane&15), f=k*32+(lane>>4)*8+j
//   Wb2: pass2 B operand, B[k=h][n=f], padded K=64, N=112.
//        [ic][nt(7)][kk(2)][lane(64)] x 16B; n=nt*16+(lane&15), h=kk*32+(lane>>4)*8+j
// ---------------------------------------------------------------------------
__global__ __launch_bounds__(256) void build_w_kernel(
    const float* __restrict__ A, const float* __restrict__ Bp,
    unsigned short* __restrict__ Wb1, unsigned short* __restrict__ Wb2)
{
    __shared__ __align__(16) float As[NF * NM];
    __shared__ __align__(16) float Bs[NM * NH];
    __shared__ __align__(16) float Ws[NF * NH];
    const int ic = blockIdx.x;  // i*NC + c
    const float* Ap  = A  + (size_t)ic * NF * NM;
    const float* Bpp = Bp + (size_t)ic * NM * NH;
    for (int idx = threadIdx.x; idx < NF * NM; idx += 256) As[idx] = Ap[idx];
    for (int idx = threadIdx.x; idx < NM * NH; idx += 256) Bs[idx] = Bpp[idx];
    __syncthreads();
    // vectorized: thread computes 4 h's (one float4) per item
    for (int idx = threadIdx.x; idx < NF * (NH / 4); idx += 256) {
        const int f  = idx / (NH / 4);
        const int hq = idx % (NH / 4);
        float4 acc = make_float4(0.f, 0.f, 0.f, 0.f);
        #pragma unroll
        for (int m = 0; m < NM; ++m) {
            const float  a = As[f * NM + m];
            const float4 b = *(const float4*)&Bs[m * NH + hq * 4];
            acc.x += a * b.x; acc.y += a * b.y; acc.z += a * b.z; acc.w += a * b.w;
        }
        *(float4*)&Ws[f * NH + hq * 4] = acc;
    }
    __syncthreads();

    // Wb1 fragments: 3*4*64 = 768 entries of 16B
    for (int e = threadIdx.x; e < 768; e += 256) {
        const int nt = e >> 8, k = (e >> 6) & 3, ln = e & 63;
        const int col = ln & 15, quad = ln >> 4;
        const int h = nt * 16 + col;
        unsigned int w[4];
        #pragma unroll
        for (int jj = 0; jj < 4; ++jj) {
            const int f0 = k * 32 + quad * 8 + jj * 2;
            const int f1 = f0 + 1;
            const unsigned int lo = (f0 < NF && h < NH) ? f2bf(Ws[f0 * NH + h]) : 0;
            const unsigned int hi = (f1 < NF && h < NH) ? f2bf(Ws[f1 * NH + h]) : 0;
            w[jj] = lo | (hi << 16);
        }
        ((u32x4*)Wb1)[(size_t)ic * 768 + e] = (u32x4){w[0], w[1], w[2], w[3]};
    }
    // Wb2 fragments: 7*2*64 = 896 entries of 16B
    for (int e = threadIdx.x; e < 896; e += 256) {
        const int nt = e >> 7, kk = (e >> 6) & 1, ln = e & 63;
        const int col = ln & 15, quad = ln >> 4;
        const int f = nt * 16 + col;
        unsigned int w[4];
        #pragma unroll
        for (int jj = 0; jj < 4; ++jj) {
            const int h0 = kk * 32 + quad * 8 + jj * 2;
            const int h1 = h0 + 1;
            const unsigned int lo = (f < NF && h0 < NH) ? f2bf(Ws[f * NH + h0]) : 0;
            const unsigned int hi = (f < NF && h1 < NH) ? f2bf(Ws[f * NH + h1]) : 0;
            w[jj] = lo | (hi << 16);
        }
        ((u32x4*)Wb2)[(size_t)ic * 896 + e] = (u32x4){w[0], w[1], w[2], w[3]};
    }
}

// ---------------------------------------------------------------------------
// Fused MFMA kernel. One block = (64 b's, one i). 512 threads = 8 waves.
// x staged to LDS (coalesced float4), A-frags built from LDS vector reads.
// B-frags stream from per-XCD L2 (i == blockIdx%8 == XCD round-robin).
// ---------------------------------------------------------------------------
__global__ __launch_bounds__(512, 2) void fused_kernel(
    const float* __restrict__ x, const float* __restrict__ mask,
    const float* __restrict__ b_final,
    const unsigned short* __restrict__ Wb1, const unsigned short* __restrict__ Wb2,
    float* __restrict__ out)
{
    __shared__ unsigned char msx[BT * NC];                   // 2560 B, 0/1 mask
    __shared__ __align__(16) unsigned char regionB[57344];   // union:
    // phase A: xs[b(64)][XPAD(104)] fp32 (26624 B)
    // phase B: hsP[g(8)][b(64)][h(48)] bf16 (49152 B)
    // phase C: outP[hb(2)][p(4)][bl(32)][f(112)] bf16 (57344 B)
    unsigned short* region = (unsigned short*)regionB;
    float* xs = (float*)regionB;

    const int tid  = threadIdx.x;
    const int lane = tid & 63;
    const int wav  = tid >> 6;       // 0..7
    const int col  = lane & 15;
    const int quad = lane >> 4;
    const int i    = blockIdx.x % NI;
    const int b0   = (blockIdx.x / NI) * BT;

    // ---- stage mask tile (bytes) + x tile (coalesced float4, rows padded) ----
    for (int idx = tid; idx < BT * NC; idx += 512) {
        const int b = idx / NC, c = idx % NC;
        msx[idx] = mask[((size_t)(b0 + b) * NI + i) * NC + c] > 0.5f ? 1 : 0;
    }
    for (int idx = tid; idx < BT * (XPAD / 4); idx += 512) {
        const int row = idx / (XPAD / 4), fq = idx % (XPAD / 4);
        float4 v = make_float4(0.f, 0.f, 0.f, 0.f);
        if (fq < NF / 4)
            v = *(const float4*)(x + ((size_t)(b0 + row) * NI + i) * NF + fq * 4);
        *(float4*)&xs[row * XPAD + fq * 4] = v;
    }
    __syncthreads();

    // ---- build X A-fragments from LDS: a1[mt][k], M=64, K=128(pad) ----
    bf16x8 a1[4][4];
    #pragma unroll
    for (int mt = 0; mt < 4; ++mt) {
        const float* xr = xs + (mt * 16 + col) * XPAD;
        #pragma unroll
        for (int k = 0; k < 4; ++k) {
            const int f0 = k * 32 + quad * 8;
            if (k < 3 || quad == 0) {
                const float4 u = *(const float4*)(xr + f0);
                const float4 v = *(const float4*)(xr + f0 + 4);
                a1[mt][k] = pack8(u, v);  // f=96..103: 100..103 are zero pad
            } else {
                a1[mt][k] = __builtin_bit_cast(bf16x8, (u32x4){0, 0, 0, 0});
            }
        }
    }
    __syncthreads();  // all waves done reading xs before hsP overwrites region

    // ---- pass 1: H[mt][nt] accumulators (M=64, N=48) ----
    f32x4 H[4][3];
    #pragma unroll
    for (int mt = 0; mt < 4; ++mt)
        #pragma unroll
        for (int nt = 0; nt < 3; ++nt)
            H[mt][nt] = (f32x4){0.f, 0.f, 0.f, 0.f};

    #pragma unroll 1
    for (int cc = 0; cc < NC / 8; ++cc) {
        const int c = wav + cc * 8;
        const u32x4* wb1 = (const u32x4*)Wb1 + (size_t)(i * NC + c) * 768;
        u32x4 braw[3][4];
        #pragma unroll
        for (int nt = 0; nt < 3; ++nt)
            #pragma unroll
            for (int k = 0; k < 4; ++k)
                braw[nt][k] = wb1[(nt * 4 + k) * 64 + lane];
        float mrow[4][4];
        #pragma unroll
        for (int mt = 0; mt < 4; ++mt)
            #pragma unroll
            for (int r = 0; r < 4; ++r)
                mrow[mt][r] = (float)msx[(mt * 16 + quad * 4 + r) * NC + c];
        #pragma unroll
        for (int mt = 0; mt < 4; ++mt) {
            #pragma unroll
            for (int nt = 0; nt < 3; ++nt) {
                f32x4 P = (f32x4){0.f, 0.f, 0.f, 0.f};
                #pragma unroll
                for (int k = 0; k < 4; ++k) {
                    P = __builtin_amdgcn_mfma_f32_16x16x32_bf16(
                        a1[mt][k], __builtin_bit_cast(bf16x8, braw[nt][k]), P, 0, 0, 0);
                }
                #pragma unroll
                for (int r = 0; r < 4; ++r)
                    H[mt][nt][r] += mrow[mt][r] * P[r];
            }
        }
    }

    // ---- write per-wave H partials (bf16): hsP[wav][b][h] ----
    #pragma unroll
    for (int mt = 0; mt < 4; ++mt)
        #pragma unroll
        for (int nt = 0; nt < 3; ++nt)
            #pragma unroll
            for (int r = 0; r < 4; ++r) {
                const int b = mt * 16 + quad * 4 + r;
                const int h = nt * 16 + col;
                region[(wav * 64 + b) * 48 + h] = f2bf(H[mt][nt][r]);
            }
    __syncthreads();

    // ---- 8-way reduce into slot 0; zero the h=40..47 pad columns ----
    for (int idx = tid; idx < BT * 48; idx += 512) {
        const int b = idx / 48, h = idx % 48;
        float s = 0.f;
        #pragma unroll
        for (int g = 0; g < 8; ++g) s += bf2f(region[(g * 64 + b) * 48 + h]);
        region[b * 48 + h] = (h < NH) ? f2bf(s) : (unsigned short)0;
    }
    __syncthreads();

    // ---- build pass2 A-frags via direct ds b128: a2[mt2][kk], K=40 pad 64 ----
    const int hb = wav >> 2;   // b-half
    const int cp = wav & 3;    // c-phase
    bf16x8 a2[2][2];
    #pragma unroll
    for (int mt2 = 0; mt2 < 2; ++mt2) {
        const int b = hb * 32 + mt2 * 16 + col;
        #pragma unroll
        for (int kk = 0; kk < 2; ++kk)
            a2[mt2][kk] = *(const bf16x8*)&region[b * 48 + kk * 32 + quad * 8];
    }
    __syncthreads();  // everyone done reading hsP before outP overwrites region

    // ---- pass 2: O[mt2][nt] accumulators (M=32, N=112) ----
    f32x4 O[2][7];
    #pragma unroll
    for (int mt2 = 0; mt2 < 2; ++mt2)
        #pragma unroll
        for (int nt = 0; nt < 7; ++nt)
            O[mt2][nt] = (f32x4){0.f, 0.f, 0.f, 0.f};

    #pragma unroll 1
    for (int cc = 0; cc < NC / 4; ++cc) {
        const int c = cp + cc * 4;
        const u32x4* wb2 = (const u32x4*)Wb2 + (size_t)(i * NC + c) * 896;
        u32x4 b2raw[7][2];
        #pragma unroll
        for (int nt = 0; nt < 7; ++nt)
            #pragma unroll
            for (int kk = 0; kk < 2; ++kk)
                b2raw[nt][kk] = wb2[(nt * 2 + kk) * 64 + lane];
        float mrow2[2][4];
        #pragma unroll
        for (int mt2 = 0; mt2 < 2; ++mt2)
            #pragma unroll
            for (int r = 0; r < 4; ++r)
                mrow2[mt2][r] = (float)msx[(hb * 32 + mt2 * 16 + quad * 4 + r) * NC + c];
        #pragma unroll
        for (int mt2 = 0; mt2 < 2; ++mt2) {
            #pragma unroll
            for (int nt = 0; nt < 7; ++nt) {
                f32x4 P = (f32x4){0.f, 0.f, 0.f, 0.f};
                #pragma unroll
                for (int kk = 0; kk < 2; ++kk) {
                    P = __builtin_amdgcn_mfma_f32_16x16x32_bf16(
                        a2[mt2][kk], __builtin_bit_cast(bf16x8, b2raw[nt][kk]), P, 0, 0, 0);
                }
                #pragma unroll
                for (int r = 0; r < 4; ++r)
                    O[mt2][nt][r] += mrow2[mt2][r] * P[r];
            }
        }
    }

    // ---- write out partials (bf16): outP[hb][cp][bl][f] ----
    #pragma unroll
    for (int mt2 = 0; mt2 < 2; ++mt2)
        #pragma unroll
        for (int nt = 0; nt < 7; ++nt)
            #pragma unroll
            for (int r = 0; r < 4; ++r) {
                const int bl = mt2 * 16 + quad * 4 + r;
                const int f  = nt * 16 + col;
                region[((hb * 4 + cp) * 32 + bl) * 112 + f] = f2bf(O[mt2][nt][r]);
            }
    __syncthreads();

    // ---- final: 4-way reduce + bias + relu, coalesced store ----
    for (int idx = tid; idx < BT * NF; idx += 512) {
        const int b = idx / NF, f = idx % NF;
        const int hb2 = b >> 5, bl = b & 31;
        float s = 0.f;
        #pragma unroll
        for (int p = 0; p < 4; ++p)
            s += bf2f(region[((hb2 * 4 + p) * 32 + bl) * 112 + f]);
        const float v = s + b_final[i * NF + f];
        out[((size_t)(b0 + b) * NI + i) * NF + f] = fmaxf(v, 0.f);
    }
}

extern "C" void kernel_launch(void* const* d_in, const int* in_sizes, int n_in,
                              void* d_out, int out_size, void* d_ws, size_t ws_size,
                              hipStream_t stream) {
    const float* x       = (const float*)d_in[0];  // (2048, 8, 100)
    const float* tk_mask = (const float*)d_in[1];  // (2048, 8, 40)
    const float* A       = (const float*)d_in[2];  // (8, 40, 100, 41)
    const float* Bp      = (const float*)d_in[3];  // (8, 40, 41, 40)
    const float* b_final = (const float*)d_in[4];  // (8, 100)
    float* out = (float*)d_out;                    // (2048, 8, 100)

    unsigned short* Wb1 = (unsigned short*)d_ws;
    unsigned short* Wb2 = Wb1 + (size_t)NI * NC * 768 * 8;

    build_w_kernel<<<NI * NC, 256, 0, stream>>>(A, Bp, Wb1, Wb2);
    fused_kernel<<<(BSZ / BT) * NI, 512, 0, stream>>>(x, tk_mask, b_final, Wb1, Wb2, out);
}